// Round 6
// baseline (261.918 us; speedup 1.0000x reference)
//
#include <hip/hip_runtime.h>

constexpr int NN = 50000;   // nodes
constexpr int NE = 600000;  // edges
constexpr int D  = 128;     // features
constexpr int NR = 8;       // relations
constexpr int NSEG = NN * NR;        // 400000 (rel, dst) segments

constexpr int SCAN_ELEMS = 1024;
constexpr int NBLK2 = (NSEG + SCAN_ELEMS - 1) / SCAN_ELEMS;   // 391

typedef unsigned int   u32;
typedef unsigned short u16;
typedef float  f32x4 __attribute__((ext_vector_type(4)));
typedef short  s16x8 __attribute__((ext_vector_type(8)));

__device__ __forceinline__ u16 f2bf(float f) {
    u32 u = __float_as_uint(f);
    u32 r = (u + 0x7fffu + ((u >> 16) & 1u)) >> 16;   // RNE
    return (u16)r;
}

__device__ __forceinline__ void async_cp16(const void* g, void* l) {
    __builtin_amdgcn_global_load_lds(
        (const __attribute__((address_space(1))) u32*)g,
        (__attribute__((address_space(3))) u32*)l, 16, 0, 0);
}

// ---------------- fused prep: count2 + convert_x + transpose_w -----------
// wt9 = 9 planes [col][k]: plane 0 = root^T, planes 1..8 = W_0..W_7^T
// cnt2 keyed by seg = rel*NN + dst  (NEW: relation-major, so a GEMM wave's
// 16 consecutive nodes have one contiguous ebin run per relation)
__global__ __launch_bounds__(256) void prep_all(const float* __restrict__ x,
                                                const float* __restrict__ weight,
                                                const float* __restrict__ root,
                                                const int* __restrict__ dst,
                                                const int* __restrict__ et,
                                                u16* __restrict__ xb,
                                                u16* __restrict__ wt9,
                                                int* __restrict__ cnt2) {
    const int NX4 = NN * D / 4;                 // 1.6M
    const int NW  = (NR + 1) * D * D;           // 147456
    int gid = blockIdx.x * 256 + threadIdx.x;
    if (gid < NX4) {
        int i = gid * 4;
        float4 v = *(const float4*)(x + i);
        ushort4 o;
        o.x = f2bf(v.x); o.y = f2bf(v.y); o.z = f2bf(v.z); o.w = f2bf(v.w);
        *(ushort4*)(xb + i) = o;
        return;
    }
    int g = gid - NX4;
    if (g < NW) {
        int p = g >> 14;          // plane 0..8
        int idx = g & 16383;      // n*128 + k  (n = output col)
        int n = idx >> 7, k = idx & 127;
        float v = (p == 0) ? root[k * D + n]
                           : weight[(size_t)(p - 1) * D * D + k * D + n];
        wt9[(size_t)p * 16384 + idx] = f2bf(v);
        return;
    }
    int e = g - NW;
    if (e < NE) atomicAdd(&cnt2[et[e] * NN + dst[e]], 1);
}

// ---------------- scans: exclusive scan of cnt2 -> offs2 -----------------
__global__ __launch_bounds__(256) void scan1(const int* __restrict__ cnt,
                                             int* __restrict__ offs,
                                             int* __restrict__ bsums) {
    __shared__ int lds[256];
    int t = threadIdx.x;
    int base = blockIdx.x * SCAN_ELEMS + t * 4;
    int v0 = (base + 0 < NSEG) ? cnt[base + 0] : 0;
    int v1 = (base + 1 < NSEG) ? cnt[base + 1] : 0;
    int v2 = (base + 2 < NSEG) ? cnt[base + 2] : 0;
    int v3 = (base + 3 < NSEG) ? cnt[base + 3] : 0;
    int s = v0 + v1 + v2 + v3;
    lds[t] = s;
    __syncthreads();
    int val = s;
    for (int off = 1; off < 256; off <<= 1) {
        int tmp = (t >= off) ? lds[t - off] : 0;
        __syncthreads();
        val += tmp;
        lds[t] = val;
        __syncthreads();
    }
    int ex = val - s;
    if (base + 0 < NSEG) offs[base + 0] = ex;
    if (base + 1 < NSEG) offs[base + 1] = ex + v0;
    if (base + 2 < NSEG) offs[base + 2] = ex + v0 + v1;
    if (base + 3 < NSEG) offs[base + 3] = ex + v0 + v1 + v2;
    if (t == 255) bsums[blockIdx.x] = val;
}

__global__ __launch_bounds__(512) void scan2(int* __restrict__ bsums) {
    __shared__ int lds[512];
    int t = threadIdx.x;
    int v = (t < NBLK2) ? bsums[t] : 0;
    lds[t] = v;
    __syncthreads();
    int val = v;
    for (int off = 1; off < 512; off <<= 1) {
        int tmp = (t >= off) ? lds[t - off] : 0;
        __syncthreads();
        val += tmp;
        lds[t] = val;
        __syncthreads();
    }
    if (t < NBLK2) bsums[t] = val - v;
}

__global__ __launch_bounds__(256) void scan3(int* __restrict__ offs,
                                             int* __restrict__ cur,
                                             const int* __restrict__ bsums) {
    int i = blockIdx.x * 256 + threadIdx.x;
    if (i < NSEG) {
        int v = offs[i] + bsums[i >> 10];
        offs[i] = v;
        cur[i]  = v;
    }
    if (i == 0) offs[NSEG] = NE;   // sentinel: end of last (rel,dst) run
}

// ---------------- bin edges by (rel, dst) --------------------------------
// payload packs BOTH endpoints: (dst<<16)|src  (both < 50000 < 2^16)
__global__ __launch_bounds__(256) void fill_bins(const int* __restrict__ src,
                                                 const int* __restrict__ dst,
                                                 const int* __restrict__ et,
                                                 int* __restrict__ cur,
                                                 int* __restrict__ ebin) {
    int e = blockIdx.x * 256 + threadIdx.x;
    if (e >= NE) return;
    int d = dst[e];
    int idx = atomicAdd(&cur[et[e] * NN + d], 1);
    ebin[idx] = (d << 16) | src[e];
}

// ---------------- fused aggregate + MFMA GEMM ----------------------------
// out[n][c] = relu( Σ_k A[n][k]*B[k][c] + bias[c] ), K = 1152 = 9 planes.
// Plane 0 A = xb (root term, global->VGPR in prologue). Planes 1..8 A =
// per-(rel,node) means computed IN-KERNEL: each wave owns 16 consecutive
// nodes; relation r's edges for them are ONE contiguous ebin run
// ((rel,dst)-keyed bins). Depth-8 gather queue with node-boundary flushes
// writes bf16 mean pairs into a PRIVATE 4KB LDS scratch (XOR-swizzled);
// A-frags ds_read from scratch one plane later. sums never touches HBM
// (was 102.4 MB write + 102.4 MB read in r5).
// B: unchanged r5 pipeline — shared dbuf LDS (2x16KB), XOR-swizzled
// granules both sides, counted vmcnt(4), fenced raw barriers.
// vmcnt discipline: all gather loads are issued AND consumed before each
// stage() (sched_barrier fenced), so at every WAITV4 the 4 newest VMEM ops
// are exactly this stage -> <=4 outstanding proves prev stage retired.
// LDS 48 KB (32 B + 16 scratch) -> 3 blocks/CU. Grid = (NN+63)/64 = 782.
__global__ __launch_bounds__(256) void rgcn_fused(const u16* __restrict__ xb,
                                                  const u16* __restrict__ wt9,
                                                  const int* __restrict__ offs2,
                                                  const int* __restrict__ ebin,
                                                  const float* __restrict__ bias,
                                                  float* __restrict__ out) {
    __shared__ __align__(16) u16 Bs[2][128 * 64];   // 32 KB shared B dbuf
    __shared__ __align__(16) u16 Sc[4][2048];       // 16 KB: 4KB/wave scratch

    const int tid  = threadIdx.x;
    const int wave = tid >> 6;
    const int lane = tid & 63;
    const int m0   = blockIdx.x * 64;
    const int n0   = m0 + wave * 16;     // wave's first node
    const int fr   = lane & 15;
    const int l4   = lane >> 4;          // 0..3
    const u32* xw  = (const u32*)xb;
    u16* scratch   = &Sc[wave][0];

    // ---- B stage mapping (identical to r5; 0 conflicts verified) ----
    int boff[4];
#pragma unroll
    for (int r = 0; r < 4; ++r) {
        int p = r * 256 + tid;
        int g = p ^ ((p >> 3) & 7);
        boff[r] = (g >> 3) * D + (g & 7) * 8;
    }
    int bidx[16];
#pragma unroll
    for (int h = 0; h < 2; ++h)
#pragma unroll
        for (int nt = 0; nt < 8; ++nt) {
            int gl = (nt * 16 + fr) * 8 + h * 4 + l4;
            int pp = gl ^ ((gl >> 3) & 7);
            bidx[h * 8 + nt] = pp * 8;
        }

    // ---- scratch A-frag read offsets (u16 units), plane-local ks=0..3 ----
    // layout: feature f of node nd at nd*128 + ((f>>3)^(nd&7))*8 + (f&7)
    int sro[4];
#pragma unroll
    for (int ks = 0; ks < 4; ++ks)
        sro[ks] = fr * 128 + (((ks * 4 + l4) ^ (fr & 7)) * 8);

    auto stage = [&](u16* bufp, const u16* Bp) {
#pragma unroll
        for (int r = 0; r < 4; ++r)
            async_cp16(Bp + boff[r], (char*)bufp + (size_t)(r * 256 + tid) * 16);
    };

    // ---- gather one relation's means for the wave's 16 nodes -> scratch ----
    auto gather = [&](int rel) {
        int nlo  = n0 < NN ? n0 : NN;
        int nhi2 = (n0 + 16) < NN ? (n0 + 16) : NN;
        int gbeg = __builtin_amdgcn_readfirstlane(offs2[rel * NN + nlo]);
        int gc   = __builtin_amdgcn_readfirstlane(offs2[rel * NN + nhi2]) - gbeg;
        float a0 = 0.f, a1 = 0.f;
        int cur = 0, cnt_cur = 0;
        int q0 = 0, q1 = 0, q2 = 0, q3 = 0, q4 = 0, q5 = 0, q6 = 0, q7 = 0;
        u32 w0 = 0, w1 = 0, w2 = 0, w3 = 0, w4 = 0, w5 = 0, w6 = 0, w7 = 0;
#define GREFILL(Q, V, IDX)                                                  \
        if ((IDX) < gc) {                                                   \
            Q = __builtin_amdgcn_readfirstlane(ebin[gbeg + (IDX)]);         \
            V = xw[(size_t)((u32)Q & 0xffffu) * 64 + lane];                 \
        }
#define GFLUSH()                                                            \
        {                                                                   \
            float inv_ = 1.0f / (float)(cnt_cur > 0 ? cnt_cur : 1);         \
            u32 lo_ = f2bf(a0 * inv_);                                      \
            u32 hi_ = f2bf(a1 * inv_);                                      \
            *(u32*)(scratch + cur * 128 + (((lane >> 2) ^ (cur & 7)) << 3)  \
                    + ((2 * lane) & 7)) = lo_ | (hi_ << 16);                \
            a0 = 0.f; a1 = 0.f; cnt_cur = 0; ++cur;                         \
        }
#define GCONSUME(Q, V)                                                      \
        {                                                                   \
            int nd_ = (int)((u32)(Q) >> 16) - n0;                           \
            while (cur < nd_) GFLUSH()                                      \
            a0 += __uint_as_float((V) << 16);                               \
            a1 += __uint_as_float((V) & 0xffff0000u);                       \
            ++cnt_cur;                                                      \
        }
        GREFILL(q0, w0, 0) GREFILL(q1, w1, 1) GREFILL(q2, w2, 2) GREFILL(q3, w3, 3)
        GREFILL(q4, w4, 4) GREFILL(q5, w5, 5) GREFILL(q6, w6, 6) GREFILL(q7, w7, 7)
        int e = 0;
        for (; e + 8 <= gc; e += 8) {
            GCONSUME(q0, w0) GREFILL(q0, w0, e + 8)
            GCONSUME(q1, w1) GREFILL(q1, w1, e + 9)
            GCONSUME(q2, w2) GREFILL(q2, w2, e + 10)
            GCONSUME(q3, w3) GREFILL(q3, w3, e + 11)
            GCONSUME(q4, w4) GREFILL(q4, w4, e + 12)
            GCONSUME(q5, w5) GREFILL(q5, w5, e + 13)
            GCONSUME(q6, w6) GREFILL(q6, w6, e + 14)
            GCONSUME(q7, w7) GREFILL(q7, w7, e + 15)
        }
        if (e + 0 < gc) GCONSUME(q0, w0)
        if (e + 1 < gc) GCONSUME(q1, w1)
        if (e + 2 < gc) GCONSUME(q2, w2)
        if (e + 3 < gc) GCONSUME(q3, w3)
        if (e + 4 < gc) GCONSUME(q4, w4)
        if (e + 5 < gc) GCONSUME(q5, w5)
        if (e + 6 < gc) GCONSUME(q6, w6)
        if (e + 7 < gc) GCONSUME(q7, w7)
        while (cur < 16) GFLUSH()
#undef GREFILL
#undef GFLUSH
#undef GCONSUME
    };

#define FENCE() __builtin_amdgcn_sched_barrier(0)
#define WAITV4() asm volatile("s_waitcnt vmcnt(4)" ::: "memory")
#define WAITV0() asm volatile("s_waitcnt vmcnt(0)" ::: "memory")
#define WAITL0() asm volatile("s_waitcnt lgkmcnt(0)" ::: "memory")
#define BAR() __builtin_amdgcn_s_barrier()
#define MFMA8(FA, HB, CB)                                                   \
    _Pragma("unroll")                                                       \
    for (int nt = 0; nt < 8; ++nt) {                                        \
        s16x8 bf = *(const s16x8*)((CB) + bidx[(HB) * 8 + nt]);             \
        acc[nt] = __builtin_amdgcn_mfma_f32_16x16x32_bf16(FA, bf, acc[nt], 0, 0, 0); \
    }

    f32x4 acc[8];
#pragma unroll
    for (int j = 0; j < 8; ++j) acc[j] = (f32x4){0.f, 0.f, 0.f, 0.f};
    s16x8 fa0, fa1, fa2, fa3;

    // ---- prologue: stage B(plane0,kof0) + load plane-0 A frags from xb ----
    stage(&Bs[0][0], wt9);
    {
        int rA = n0 + fr; if (rA > NN - 1) rA = NN - 1;
        const u16* ap = xb + (size_t)rA * D + l4 * 8;
        fa0 = *(const s16x8*)(ap);
        fa1 = *(const s16x8*)(ap + 32);
        fa2 = *(const s16x8*)(ap + 64);
        fa3 = *(const s16x8*)(ap + 96);
    }
    FENCE();

    // ---- plane 0 (root term) + gather relation 0 ----
    gather(0);
    FENCE();
    stage(&Bs[1][0], wt9 + 0 * 16384 + 64);
    FENCE(); WAITV4(); BAR(); FENCE();
    MFMA8(fa0, 0, &Bs[0][0]) MFMA8(fa1, 1, &Bs[0][0])
    WAITL0(); FENCE(); BAR(); FENCE();
    stage(&Bs[0][0], wt9 + 1 * 16384);
    FENCE(); WAITV4(); BAR(); FENCE();
    MFMA8(fa2, 0, &Bs[1][0]) MFMA8(fa3, 1, &Bs[1][0])
    WAITL0(); FENCE(); BAR(); FENCE();

    // ---- planes 1..7: frag-read scratch, gather next relation ----
    for (int pl = 1; pl < 8; ++pl) {
        fa0 = *(const s16x8*)(scratch + sro[0]);
        fa1 = *(const s16x8*)(scratch + sro[1]);
        fa2 = *(const s16x8*)(scratch + sro[2]);
        fa3 = *(const s16x8*)(scratch + sro[3]);
        WAITL0(); FENCE();            // frags in regs; scratch reusable
        gather(pl);                   // writes plane pl+1 means
        FENCE();
        stage(&Bs[1][0], wt9 + (size_t)pl * 16384 + 64);
        FENCE(); WAITV4(); BAR(); FENCE();
        MFMA8(fa0, 0, &Bs[0][0]) MFMA8(fa1, 1, &Bs[0][0])
        WAITL0(); FENCE(); BAR(); FENCE();
        stage(&Bs[0][0], wt9 + (size_t)(pl + 1) * 16384);
        FENCE(); WAITV4(); BAR(); FENCE();
        MFMA8(fa2, 0, &Bs[1][0]) MFMA8(fa3, 1, &Bs[1][0])
        WAITL0(); FENCE(); BAR(); FENCE();
    }

    // ---- plane 8: last frag-read, no gather, final half drains vmcnt ----
    fa0 = *(const s16x8*)(scratch + sro[0]);
    fa1 = *(const s16x8*)(scratch + sro[1]);
    fa2 = *(const s16x8*)(scratch + sro[2]);
    fa3 = *(const s16x8*)(scratch + sro[3]);
    WAITL0(); FENCE();
    stage(&Bs[1][0], wt9 + (size_t)8 * 16384 + 64);
    FENCE(); WAITV4(); BAR(); FENCE();
    MFMA8(fa0, 0, &Bs[0][0]) MFMA8(fa1, 1, &Bs[0][0])
    WAITL0(); FENCE(); BAR(); FENCE();
    WAITV0(); BAR(); FENCE();
    MFMA8(fa2, 0, &Bs[1][0]) MFMA8(fa3, 1, &Bs[1][0])

#undef FENCE
#undef WAITV4
#undef WAITV0
#undef WAITL0
#undef BAR
#undef MFMA8

    // ---- epilogue: C/D layout col=lane&15, row=(lane>>4)*4+reg ----
    const int cl = lane & 15;
    const int rq = l4 * 4;
#pragma unroll
    for (int nt = 0; nt < 8; ++nt) {
        int col = nt * 16 + cl;
        float bv = bias[col];
#pragma unroll
        for (int reg = 0; reg < 4; ++reg) {
            int n = m0 + wave * 16 + rq + reg;
            if (n < NN) {
                float v = acc[nt][reg] + bv;
                out[(size_t)n * D + col] = fmaxf(v, 0.0f);
            }
        }
    }
}

extern "C" void kernel_launch(void* const* d_in, const int* in_sizes, int n_in,
                              void* d_out, int out_size, void* d_ws, size_t ws_size,
                              hipStream_t stream) {
    const float* x      = (const float*)d_in[0];
    const int*   ei     = (const int*)d_in[1];
    const int*   et     = (const int*)d_in[2];
    const float* weight = (const float*)d_in[3];
    const float* root   = (const float*)d_in[4];
    const float* bias   = (const float*)d_in[5];
    float* out = (float*)d_out;
    const int* srcv = ei;
    const int* dstv = ei + NE;

    // ws: ints [cnt2 NSEG][cur2 NSEG][offs2 NSEG+1][bsums 512][ebin NE],
    // then u16 [xb NN*D][wt9 9*D*D]   (sums eliminated by fusion)
    int* cnt2  = (int*)d_ws;
    int* cur2  = cnt2 + NSEG;
    int* offs2 = cur2 + NSEG;
    int* bsums = offs2 + NSEG + 1;
    int* ebin  = bsums + 512;
    size_t fixed_b  = ((char*)(ebin + NE) - (char*)d_ws);
    size_t fixed_al = (fixed_b + 255) & ~(size_t)255;
    u16* xb   = (u16*)((char*)d_ws + fixed_al);
    u16* wt9  = xb + (size_t)NN * D;

    hipMemsetAsync(cnt2, 0, NSEG * sizeof(int), stream);

    const int PREP = NN * D / 4 + (NR + 1) * D * D + NE;
    prep_all<<<(PREP + 255) / 256, 256, 0, stream>>>(x, weight, root, dstv, et,
                                                     xb, wt9, cnt2);

    scan1<<<NBLK2, 256, 0, stream>>>(cnt2, offs2, bsums);
    scan2<<<1, 512, 0, stream>>>(bsums);
    scan3<<<(NSEG + 256) / 256, 256, 0, stream>>>(offs2, cur2, bsums);
    fill_bins<<<(NE + 255) / 256, 256, 0, stream>>>(srcv, dstv, et, cur2, ebin);

    // BM=64 -> grid = (NN+63)/64 = 782 blocks (grid/BM must match!)
    rgcn_fused<<<(NN + 63) / 64, 256, 0, stream>>>(xb, wt9, offs2, ebin, bias, out);
}

// Round 7
// 218.591 us; speedup vs baseline: 1.1982x; 1.1982x over previous
//
#include <hip/hip_runtime.h>

constexpr int NN = 50000;   // nodes
constexpr int NE = 600000;  // edges
constexpr int D  = 128;     // features
constexpr int NR = 8;       // relations
constexpr int KT = (NR + 1) * D;     // 1152 total K
constexpr int NSEG = NN * NR;        // 400000 (dst, rel) segments

constexpr int SCAN_ELEMS = 1024;
constexpr int NBLK2 = (NSEG + SCAN_ELEMS - 1) / SCAN_ELEMS;   // 391

typedef unsigned int   u32;
typedef unsigned short u16;
typedef float  f32x4 __attribute__((ext_vector_type(4)));
typedef short  s16x8 __attribute__((ext_vector_type(8)));

__device__ __forceinline__ u16 f2bf(float f) {
    u32 u = __float_as_uint(f);
    u32 r = (u + 0x7fffu + ((u >> 16) & 1u)) >> 16;   // RNE
    return (u16)r;
}

__device__ __forceinline__ void async_cp16(const void* g, void* l) {
    __builtin_amdgcn_global_load_lds(
        (const __attribute__((address_space(1))) u32*)g,
        (__attribute__((address_space(3))) u32*)l, 16, 0, 0);
}

// ---------------- fused prep: count2 + convert_x + transpose_w -----------
// wt9 = 9 planes [col][k]: plane 0 = root^T, planes 1..8 = W_0..W_7^T
__global__ __launch_bounds__(256) void prep_all(const float* __restrict__ x,
                                                const float* __restrict__ weight,
                                                const float* __restrict__ root,
                                                const int* __restrict__ dst,
                                                const int* __restrict__ et,
                                                u16* __restrict__ xb,
                                                u16* __restrict__ wt9,
                                                int* __restrict__ cnt2) {
    const int NX4 = NN * D / 4;                 // 1.6M
    const int NW  = (NR + 1) * D * D;           // 147456
    int gid = blockIdx.x * 256 + threadIdx.x;
    if (gid < NX4) {
        int i = gid * 4;
        float4 v = *(const float4*)(x + i);
        ushort4 o;
        o.x = f2bf(v.x); o.y = f2bf(v.y); o.z = f2bf(v.z); o.w = f2bf(v.w);
        *(ushort4*)(xb + i) = o;
        return;
    }
    int g = gid - NX4;
    if (g < NW) {
        int p = g >> 14;          // plane 0..8
        int idx = g & 16383;      // n*128 + k  (n = output col)
        int n = idx >> 7, k = idx & 127;
        float v = (p == 0) ? root[k * D + n]
                           : weight[(size_t)(p - 1) * D * D + k * D + n];
        wt9[(size_t)p * 16384 + idx] = f2bf(v);
        return;
    }
    int e = g - NW;
    if (e < NE) atomicAdd(&cnt2[dst[e] * NR + et[e]], 1);
}

// ---------------- scans: exclusive scan of cnt2 -> offs2 -----------------
__global__ __launch_bounds__(256) void scan1(const int* __restrict__ cnt,
                                             int* __restrict__ offs,
                                             int* __restrict__ bsums) {
    __shared__ int lds[256];
    int t = threadIdx.x;
    int base = blockIdx.x * SCAN_ELEMS + t * 4;
    int v0 = (base + 0 < NSEG) ? cnt[base + 0] : 0;
    int v1 = (base + 1 < NSEG) ? cnt[base + 1] : 0;
    int v2 = (base + 2 < NSEG) ? cnt[base + 2] : 0;
    int v3 = (base + 3 < NSEG) ? cnt[base + 3] : 0;
    int s = v0 + v1 + v2 + v3;
    lds[t] = s;
    __syncthreads();
    int val = s;
    for (int off = 1; off < 256; off <<= 1) {
        int tmp = (t >= off) ? lds[t - off] : 0;
        __syncthreads();
        val += tmp;
        lds[t] = val;
        __syncthreads();
    }
    int ex = val - s;
    if (base + 0 < NSEG) offs[base + 0] = ex;
    if (base + 1 < NSEG) offs[base + 1] = ex + v0;
    if (base + 2 < NSEG) offs[base + 2] = ex + v0 + v1;
    if (base + 3 < NSEG) offs[base + 3] = ex + v0 + v1 + v2;
    if (t == 255) bsums[blockIdx.x] = val;
}

__global__ __launch_bounds__(512) void scan2(int* __restrict__ bsums) {
    __shared__ int lds[512];
    int t = threadIdx.x;
    int v = (t < NBLK2) ? bsums[t] : 0;
    lds[t] = v;
    __syncthreads();
    int val = v;
    for (int off = 1; off < 512; off <<= 1) {
        int tmp = (t >= off) ? lds[t - off] : 0;
        __syncthreads();
        val += tmp;
        lds[t] = val;
        __syncthreads();
    }
    if (t < NBLK2) bsums[t] = val - v;
}

__global__ __launch_bounds__(256) void scan3(int* __restrict__ offs,
                                             int* __restrict__ cur,
                                             const int* __restrict__ bsums) {
    int i = blockIdx.x * 256 + threadIdx.x;
    if (i < NSEG) {
        int v = offs[i] + bsums[i >> 10];
        offs[i] = v;
        cur[i]  = v;
    }
    if (i == 0) offs[NSEG] = NE;
}

// ---------------- bin edges by (dst, rel) --------------------------------
__global__ __launch_bounds__(256) void fill_bins(const int* __restrict__ src,
                                                 const int* __restrict__ dst,
                                                 const int* __restrict__ et,
                                                 int* __restrict__ cur,
                                                 int* __restrict__ ebin) {
    int e = blockIdx.x * 256 + threadIdx.x;
    if (e >= NE) return;
    int r = et[e];
    int idx = atomicAdd(&cur[dst[e] * NR + r], 1);
    ebin[idx] = (r << 16) | src[e];   // src < 50000 < 2^16
}

// ---------------- aggregation: relation-sorted, boundary-flush -----------
__global__ __launch_bounds__(128) void aggregate_kernel(const u32* __restrict__ xw,
                                                        const int* __restrict__ offs2,
                                                        const int* __restrict__ ebin,
                                                        u32* __restrict__ sw) {
    const int lane = threadIdx.x & 63;
    const int n = blockIdx.x * 2 + (threadIdx.x >> 6);
    if (n >= NN) return;
    const int beg = __builtin_amdgcn_readfirstlane(offs2[n * NR]);
    const int c   = __builtin_amdgcn_readfirstlane(offs2[n * NR + NR]) - beg;

    float a0 = 0.f, a1 = 0.f;
    int r_cur = 0, cnt_cur = 0;

    int q0 = 0, q1 = 0, q2 = 0, q3 = 0, q4 = 0, q5 = 0, q6 = 0, q7 = 0;
    u32 v0 = 0, v1 = 0, v2 = 0, v3 = 0, v4 = 0, v5 = 0, v6 = 0, v7 = 0;

#define REFILL(Q, V, IDX)                                                   \
    if ((IDX) < c) {                                                        \
        Q = __builtin_amdgcn_readfirstlane(ebin[beg + (IDX)]);              \
        V = xw[(size_t)((u32)Q & 0xffffu) * 64 + lane];                     \
    }
#define FLUSH()                                                             \
    {                                                                       \
        float inv_ = 1.0f / (float)(cnt_cur > 0 ? cnt_cur : 1);             \
        u32 lo16_ = f2bf(a0 * inv_);                                        \
        u32 hi16_ = f2bf(a1 * inv_);                                        \
        sw[((size_t)r_cur * NN + n) * 64 + lane] = lo16_ | (hi16_ << 16);   \
        a0 = 0.f; a1 = 0.f; cnt_cur = 0; ++r_cur;                           \
    }
#define CONSUME(Q, V)                                                       \
    {                                                                       \
        int rj_ = (int)((u32)(Q) >> 16);                                    \
        while (r_cur < rj_) FLUSH()                                         \
        a0 += __uint_as_float((V) << 16);                                   \
        a1 += __uint_as_float((V) & 0xffff0000u);                           \
        ++cnt_cur;                                                          \
    }

    REFILL(q0, v0, 0) REFILL(q1, v1, 1) REFILL(q2, v2, 2) REFILL(q3, v3, 3)
    REFILL(q4, v4, 4) REFILL(q5, v5, 5) REFILL(q6, v6, 6) REFILL(q7, v7, 7)

    int e = 0;
    for (; e + 8 <= c; e += 8) {
        CONSUME(q0, v0) REFILL(q0, v0, e + 8)
        CONSUME(q1, v1) REFILL(q1, v1, e + 9)
        CONSUME(q2, v2) REFILL(q2, v2, e + 10)
        CONSUME(q3, v3) REFILL(q3, v3, e + 11)
        CONSUME(q4, v4) REFILL(q4, v4, e + 12)
        CONSUME(q5, v5) REFILL(q5, v5, e + 13)
        CONSUME(q6, v6) REFILL(q6, v6, e + 14)
        CONSUME(q7, v7) REFILL(q7, v7, e + 15)
    }
    if (e + 0 < c) CONSUME(q0, v0)
    if (e + 1 < c) CONSUME(q1, v1)
    if (e + 2 < c) CONSUME(q2, v2)
    if (e + 3 < c) CONSUME(q3, v3)
    if (e + 4 < c) CONSUME(q4, v4)
    if (e + 5 < c) CONSUME(q5, v5)
    if (e + 6 < c) CONSUME(q6, v6)
    if (e + 7 < c) CONSUME(q7, v7)

    while (r_cur < NR) FLUSH()
#undef REFILL
#undef FLUSH
#undef CONSUME
}

// ---------------- fused MFMA GEMM: 2-phase, counted vmcnt, fenced --------
// out[n][c] = relu( Σ_k A[n][k]*B[k][c] + bias[c] ), K = 1152, BK = 64.
// BM=64 -> grid (NN+63)/64 = 782 blocks. 4 waves x 16 rows x 128 cols.
// A: direct global->VGPR with DEPTH-2 prefetch (r7: A rows come from HBM,
//    ~900 cy; one iteration (~400 cy) didn't cover it -> vmcnt stall was
//    the r5 gemm's ~1.7x-over-floor gap). Triple reg set, explicit rotate.
// B: SHARED double-buffered LDS panel (2 x 16 KB), XOR-swizzled granules
//    (g -> g ^ ((g>>3)&7)) on BOTH global source and ds_read addr
//    (0 bank conflicts, verified r1).
// vmcnt derivation (per iter issues S(it+1)=4, A(it+2)=2):
//   ops after S(it) = A(it+1)2 + S(it+1)4 + A(it+2)2 = 8  -> vmcnt(8)
//   it=16: A(18) absent -> 6                              -> vmcnt(6)
//   final tile: vmcnt(0).
// s_barrier is NOT a compiler fence; sched_barrier(0) pins the phases.
__global__ __launch_bounds__(256) void mfma_gemm(const u16* __restrict__ xb,
                                                 const u16* __restrict__ sums,
                                                 const u16* __restrict__ wt9,
                                                 const float* __restrict__ bias,
                                                 float* __restrict__ out) {
    __shared__ __align__(16) u16 Bs[2][128 * 64];   // 32 KB

    const int tid  = threadIdx.x;
    const int wave = tid >> 6;
    const int lane = tid & 63;
    const int m0   = blockIdx.x * 64;
    const int fr   = lane & 15;
    const int l4   = lane >> 4;          // 0..3
    const int fk   = l4 * 8;

    // stage mapping: 1024 granules of 16B per buffer, 4 rounds x 256 thr.
    int boff[4];
#pragma unroll
    for (int r = 0; r < 4; ++r) {
        int p = r * 256 + tid;
        int g = p ^ ((p >> 3) & 7);
        boff[r] = (g >> 3) * D + (g & 7) * 8;     // u16 offset in [col][k] panel
    }
    // read mapping: frag (h,nt): logical g = (nt*16+fr)*8 + h*4 + l4
    int bidx[16];
#pragma unroll
    for (int h = 0; h < 2; ++h)
#pragma unroll
        for (int nt = 0; nt < 8; ++nt) {
            int gl = (nt * 16 + fr) * 8 + h * 4 + l4;
            int pp = gl ^ ((gl >> 3) & 7);
            bidx[h * 8 + nt] = pp * 8;             // u16 index
        }

    int r0 = m0 + wave * 16 + fr;  if (r0 > NN - 1) r0 = NN - 1;   // tail clamp
    const size_t aoff = (size_t)r0 * D + fk;

    auto stage = [&](u16* bufp, const u16* Bp) {
#pragma unroll
        for (int r = 0; r < 4; ++r)
            async_cp16(Bp + boff[r], (char*)bufp + (size_t)(r * 256 + tid) * 16);
    };

    f32x4 acc[8];
#pragma unroll
    for (int j = 0; j < 8; ++j) acc[j] = (f32x4){0.f, 0.f, 0.f, 0.f};

    // K-plan: 18 iters of BK=64; plane = it>>1 (0 = root/xb), kof = (it&1)*64
    // prologue: S(0) + A(0) + A(1)   (iters 0 and 1 are both plane 0)
    stage(&Bs[0][0], wt9);
    s16x8 a0c  = *(const s16x8*)(xb + aoff);          // A(0): kof 0
    s16x8 a1c  = *(const s16x8*)(xb + aoff + 32);
    s16x8 a0n1 = *(const s16x8*)(xb + aoff + 64);     // A(1): kof 64
    s16x8 a1n1 = *(const s16x8*)(xb + aoff + 96);
    s16x8 a0n2 = a0n1, a1n2 = a1n1;
    __builtin_amdgcn_sched_barrier(0);   // pin prologue VMEM group (FIFO count)

    for (int it = 0; it < 17; ++it) {
        const int nx  = it + 1;
        const int npl = nx >> 1;
        const int kof = (nx & 1) * 64;
        u16* nbuf = &Bs[nx & 1][0];
        const u16* cbuf = &Bs[it & 1][0];

        stage(nbuf, wt9 + npl * 16384 + kof);          // S(it+1)
        if (it + 2 <= 17) {                            // A(it+2)
            const int p2 = (it + 2) >> 1;
            const int k2 = ((it + 2) & 1) * 64;
            const u16* Ap2 = ((p2 == 0) ? xb
                              : sums + (size_t)(p2 - 1) * NN * D) + k2;
            a0n2 = *(const s16x8*)(Ap2 + aoff);
            a1n2 = *(const s16x8*)(Ap2 + aoff + 32);
        }
        __builtin_amdgcn_sched_barrier(0);
        if (it < 16) { asm volatile("s_waitcnt vmcnt(8)" ::: "memory"); }
        else         { asm volatile("s_waitcnt vmcnt(6)" ::: "memory"); }
        __builtin_amdgcn_s_barrier();                  // all waves: cbuf ready
        __builtin_amdgcn_sched_barrier(0);             // no ds_read hoists above
#pragma unroll
        for (int nt = 0; nt < 8; ++nt) {
            s16x8 bf = *(const s16x8*)(cbuf + bidx[nt]);
            acc[nt] = __builtin_amdgcn_mfma_f32_16x16x32_bf16(a0c, bf, acc[nt], 0, 0, 0);
        }
#pragma unroll
        for (int nt = 0; nt < 8; ++nt) {
            s16x8 bf = *(const s16x8*)(cbuf + bidx[8 + nt]);
            acc[nt] = __builtin_amdgcn_mfma_f32_16x16x32_bf16(a1c, bf, acc[nt], 0, 0, 0);
        }
        asm volatile("s_waitcnt lgkmcnt(0)" ::: "memory"); // reads of cbuf done
        __builtin_amdgcn_sched_barrier(0);
        __builtin_amdgcn_s_barrier();                      // WAR guard
        __builtin_amdgcn_sched_barrier(0);                 // no next-stage hoists
        a0c = a0n1; a1c = a1n1;                            // rotate A queue
        a0n1 = a0n2; a1n1 = a1n2;
    }
    // final tile (it=17, buffer 1): full drain ok, nothing left to overlap
    asm volatile("s_waitcnt vmcnt(0)" ::: "memory");
    __builtin_amdgcn_s_barrier();
    __builtin_amdgcn_sched_barrier(0);
    {
        const u16* cbuf = &Bs[1][0];
#pragma unroll
        for (int nt = 0; nt < 8; ++nt) {
            s16x8 bf = *(const s16x8*)(cbuf + bidx[nt]);
            acc[nt] = __builtin_amdgcn_mfma_f32_16x16x32_bf16(a0c, bf, acc[nt], 0, 0, 0);
        }
#pragma unroll
        for (int nt = 0; nt < 8; ++nt) {
            s16x8 bf = *(const s16x8*)(cbuf + bidx[8 + nt]);
            acc[nt] = __builtin_amdgcn_mfma_f32_16x16x32_bf16(a1c, bf, acc[nt], 0, 0, 0);
        }
    }

    // epilogue: C/D layout col=lane&15, row=(lane>>4)*4+reg
    const int cl = lane & 15;
    const int rq = l4 * 4;
#pragma unroll
    for (int nt = 0; nt < 8; ++nt) {
        int col = nt * 16 + cl;
        float bv = bias[col];
#pragma unroll
        for (int reg = 0; reg < 4; ++reg) {
            int n = m0 + wave * 16 + rq + reg;
            if (n < NN) {
                float v = acc[nt][reg] + bv;
                out[(size_t)n * D + col] = fmaxf(v, 0.0f);
            }
        }
    }
}

extern "C" void kernel_launch(void* const* d_in, const int* in_sizes, int n_in,
                              void* d_out, int out_size, void* d_ws, size_t ws_size,
                              hipStream_t stream) {
    const float* x      = (const float*)d_in[0];
    const int*   ei     = (const int*)d_in[1];
    const int*   et     = (const int*)d_in[2];
    const float* weight = (const float*)d_in[3];
    const float* root   = (const float*)d_in[4];
    const float* bias   = (const float*)d_in[5];
    float* out = (float*)d_out;
    const int* srcv = ei;
    const int* dstv = ei + NE;

    // ws: ints [cnt2 NSEG][cur2 NSEG][offs2 NSEG+1][bsums 512][ebin NE],
    // then u16 [xb NN*D][sums NR*NN*D][wt9 9*D*D]
    int* cnt2  = (int*)d_ws;
    int* cur2  = cnt2 + NSEG;
    int* offs2 = cur2 + NSEG;
    int* bsums = offs2 + NSEG + 1;
    int* ebin  = bsums + 512;
    size_t fixed_b  = ((char*)(ebin + NE) - (char*)d_ws);
    size_t fixed_al = (fixed_b + 255) & ~(size_t)255;
    u16* xb   = (u16*)((char*)d_ws + fixed_al);
    u16* sums = xb + (size_t)NN * D;
    u16* wt9  = sums + (size_t)NR * NN * D;

    hipMemsetAsync(cnt2, 0, NSEG * sizeof(int), stream);

    const int PREP = NN * D / 4 + (NR + 1) * D * D + NE;
    prep_all<<<(PREP + 255) / 256, 256, 0, stream>>>(x, weight, root, dstv, et,
                                                     xb, wt9, cnt2);

    scan1<<<NBLK2, 256, 0, stream>>>(cnt2, offs2, bsums);
    scan2<<<1, 512, 0, stream>>>(bsums);
    scan3<<<(NSEG + 256) / 256, 256, 0, stream>>>(offs2, cur2, bsums);
    fill_bins<<<(NE + 255) / 256, 256, 0, stream>>>(srcv, dstv, et, cur2, ebin);

    aggregate_kernel<<<(NN + 1) / 2, 128, 0, stream>>>((const u32*)xb, offs2, ebin,
                                                       (u32*)sums);

    // BM=64 -> 782 blocks (grid/BM must match!)
    mfma_gemm<<<(NN + 63) / 64, 256, 0, stream>>>(xb, sums, wt9, bias, out);
}

// Round 8
// 215.840 us; speedup vs baseline: 1.2135x; 1.0127x over previous
//
#include <hip/hip_runtime.h>

constexpr int NN = 50000;   // nodes
constexpr int NE = 600000;  // edges
constexpr int D  = 128;     // features
constexpr int NR = 8;       // relations
constexpr int KT = (NR + 1) * D;     // 1152 total K
constexpr int NSEG = NN * NR;        // 400000 (dst, rel) segments

constexpr int SCAN_ELEMS = 1024;
constexpr int NBLK2 = (NSEG + SCAN_ELEMS - 1) / SCAN_ELEMS;   // 391

constexpr int BM = 128;              // gemm row-tile; grid derives from THIS
constexpr int GEMM_GRID = (NN + BM - 1) / BM;   // 391

typedef unsigned int   u32;
typedef unsigned short u16;
typedef float  f32x4 __attribute__((ext_vector_type(4)));
typedef short  s16x8 __attribute__((ext_vector_type(8)));

__device__ __forceinline__ u16 f2bf(float f) {
    u32 u = __float_as_uint(f);
    u32 r = (u + 0x7fffu + ((u >> 16) & 1u)) >> 16;   // RNE
    return (u16)r;
}

__device__ __forceinline__ void async_cp16(const void* g, void* l) {
    __builtin_amdgcn_global_load_lds(
        (const __attribute__((address_space(1))) u32*)g,
        (__attribute__((address_space(3))) u32*)l, 16, 0, 0);
}

// ---------------- fused prep: count2 + convert_x + transpose_w -----------
// wt9 = 9 planes [col][k]: plane 0 = root^T, planes 1..8 = W_0..W_7^T
__global__ __launch_bounds__(256) void prep_all(const float* __restrict__ x,
                                                const float* __restrict__ weight,
                                                const float* __restrict__ root,
                                                const int* __restrict__ dst,
                                                const int* __restrict__ et,
                                                u16* __restrict__ xb,
                                                u16* __restrict__ wt9,
                                                int* __restrict__ cnt2) {
    const int NX4 = NN * D / 4;                 // 1.6M
    const int NW  = (NR + 1) * D * D;           // 147456
    int gid = blockIdx.x * 256 + threadIdx.x;
    if (gid < NX4) {
        int i = gid * 4;
        float4 v = *(const float4*)(x + i);
        ushort4 o;
        o.x = f2bf(v.x); o.y = f2bf(v.y); o.z = f2bf(v.z); o.w = f2bf(v.w);
        *(ushort4*)(xb + i) = o;
        return;
    }
    int g = gid - NX4;
    if (g < NW) {
        int p = g >> 14;          // plane 0..8
        int idx = g & 16383;      // n*128 + k  (n = output col)
        int n = idx >> 7, k = idx & 127;
        float v = (p == 0) ? root[k * D + n]
                           : weight[(size_t)(p - 1) * D * D + k * D + n];
        wt9[(size_t)p * 16384 + idx] = f2bf(v);
        return;
    }
    int e = g - NW;
    if (e < NE) atomicAdd(&cnt2[dst[e] * NR + et[e]], 1);
}

// ---------------- scans: exclusive scan of cnt2 -> offs2 -----------------
__global__ __launch_bounds__(256) void scan1(const int* __restrict__ cnt,
                                             int* __restrict__ offs,
                                             int* __restrict__ bsums) {
    __shared__ int lds[256];
    int t = threadIdx.x;
    int base = blockIdx.x * SCAN_ELEMS + t * 4;
    int v0 = (base + 0 < NSEG) ? cnt[base + 0] : 0;
    int v1 = (base + 1 < NSEG) ? cnt[base + 1] : 0;
    int v2 = (base + 2 < NSEG) ? cnt[base + 2] : 0;
    int v3 = (base + 3 < NSEG) ? cnt[base + 3] : 0;
    int s = v0 + v1 + v2 + v3;
    lds[t] = s;
    __syncthreads();
    int val = s;
    for (int off = 1; off < 256; off <<= 1) {
        int tmp = (t >= off) ? lds[t - off] : 0;
        __syncthreads();
        val += tmp;
        lds[t] = val;
        __syncthreads();
    }
    int ex = val - s;
    if (base + 0 < NSEG) offs[base + 0] = ex;
    if (base + 1 < NSEG) offs[base + 1] = ex + v0;
    if (base + 2 < NSEG) offs[base + 2] = ex + v0 + v1;
    if (base + 3 < NSEG) offs[base + 3] = ex + v0 + v1 + v2;
    if (t == 255) bsums[blockIdx.x] = val;
}

__global__ __launch_bounds__(512) void scan2(int* __restrict__ bsums) {
    __shared__ int lds[512];
    int t = threadIdx.x;
    int v = (t < NBLK2) ? bsums[t] : 0;
    lds[t] = v;
    __syncthreads();
    int val = v;
    for (int off = 1; off < 512; off <<= 1) {
        int tmp = (t >= off) ? lds[t - off] : 0;
        __syncthreads();
        val += tmp;
        lds[t] = val;
        __syncthreads();
    }
    if (t < NBLK2) bsums[t] = val - v;
}

__global__ __launch_bounds__(256) void scan3(int* __restrict__ offs,
                                             int* __restrict__ cur,
                                             const int* __restrict__ bsums) {
    int i = blockIdx.x * 256 + threadIdx.x;
    if (i < NSEG) {
        int v = offs[i] + bsums[i >> 10];
        offs[i] = v;
        cur[i]  = v;
    }
    if (i == 0) offs[NSEG] = NE;
}

// ---------------- bin edges by (dst, rel) --------------------------------
__global__ __launch_bounds__(256) void fill_bins(const int* __restrict__ src,
                                                 const int* __restrict__ dst,
                                                 const int* __restrict__ et,
                                                 int* __restrict__ cur,
                                                 int* __restrict__ ebin) {
    int e = blockIdx.x * 256 + threadIdx.x;
    if (e >= NE) return;
    int r = et[e];
    int idx = atomicAdd(&cur[dst[e] * NR + r], 1);
    ebin[idx] = (r << 16) | src[e];   // src < 50000 < 2^16
}

// ---------------- aggregation: relation-sorted, boundary-flush -----------
__global__ __launch_bounds__(128) void aggregate_kernel(const u32* __restrict__ xw,
                                                        const int* __restrict__ offs2,
                                                        const int* __restrict__ ebin,
                                                        u32* __restrict__ sw) {
    const int lane = threadIdx.x & 63;
    const int n = blockIdx.x * 2 + (threadIdx.x >> 6);
    if (n >= NN) return;
    const int beg = __builtin_amdgcn_readfirstlane(offs2[n * NR]);
    const int c   = __builtin_amdgcn_readfirstlane(offs2[n * NR + NR]) - beg;

    float a0 = 0.f, a1 = 0.f;
    int r_cur = 0, cnt_cur = 0;

    int q0 = 0, q1 = 0, q2 = 0, q3 = 0, q4 = 0, q5 = 0, q6 = 0, q7 = 0;
    u32 v0 = 0, v1 = 0, v2 = 0, v3 = 0, v4 = 0, v5 = 0, v6 = 0, v7 = 0;

#define REFILL(Q, V, IDX)                                                   \
    if ((IDX) < c) {                                                        \
        Q = __builtin_amdgcn_readfirstlane(ebin[beg + (IDX)]);              \
        V = xw[(size_t)((u32)Q & 0xffffu) * 64 + lane];                     \
    }
#define FLUSH()                                                             \
    {                                                                       \
        float inv_ = 1.0f / (float)(cnt_cur > 0 ? cnt_cur : 1);             \
        u32 lo16_ = f2bf(a0 * inv_);                                        \
        u32 hi16_ = f2bf(a1 * inv_);                                        \
        sw[((size_t)r_cur * NN + n) * 64 + lane] = lo16_ | (hi16_ << 16);   \
        a0 = 0.f; a1 = 0.f; cnt_cur = 0; ++r_cur;                           \
    }
#define CONSUME(Q, V)                                                       \
    {                                                                       \
        int rj_ = (int)((u32)(Q) >> 16);                                    \
        while (r_cur < rj_) FLUSH()                                         \
        a0 += __uint_as_float((V) << 16);                                   \
        a1 += __uint_as_float((V) & 0xffff0000u);                           \
        ++cnt_cur;                                                          \
    }

    REFILL(q0, v0, 0) REFILL(q1, v1, 1) REFILL(q2, v2, 2) REFILL(q3, v3, 3)
    REFILL(q4, v4, 4) REFILL(q5, v5, 5) REFILL(q6, v6, 6) REFILL(q7, v7, 7)

    int e = 0;
    for (; e + 8 <= c; e += 8) {
        CONSUME(q0, v0) REFILL(q0, v0, e + 8)
        CONSUME(q1, v1) REFILL(q1, v1, e + 9)
        CONSUME(q2, v2) REFILL(q2, v2, e + 10)
        CONSUME(q3, v3) REFILL(q3, v3, e + 11)
        CONSUME(q4, v4) REFILL(q4, v4, e + 12)
        CONSUME(q5, v5) REFILL(q5, v5, e + 13)
        CONSUME(q6, v6) REFILL(q6, v6, e + 14)
        CONSUME(q7, v7) REFILL(q7, v7, e + 15)
    }
    if (e + 0 < c) CONSUME(q0, v0)
    if (e + 1 < c) CONSUME(q1, v1)
    if (e + 2 < c) CONSUME(q2, v2)
    if (e + 3 < c) CONSUME(q3, v3)
    if (e + 4 < c) CONSUME(q4, v4)
    if (e + 5 < c) CONSUME(q5, v5)
    if (e + 6 < c) CONSUME(q6, v6)
    if (e + 7 < c) CONSUME(q7, v7)

    while (r_cur < NR) FLUSH()
#undef REFILL
#undef FLUSH
#undef CONSUME
}

// ---------------- fused MFMA GEMM: BM=128, 2-phase, counted vmcnt --------
// out[n][c] = relu( Σ_k A[n][k]*B[k][c] + bias[c] ), K = 1152, BK = 64.
// r8: BM 64 -> 128 (4 waves x 32 rows x 128 cols). Rationale: three sync
// structures all pinned at ~41 us / ~2 TB/s -> byte-bound, not latency.
// BM=128 halves the B L2 stream (225 -> 112 MB: 391 blocks x 288 KB wt9)
// and each B ds_read_b128 now feeds 2 MFMAs. A traffic unchanged (BN stays
// full-width -> every A row read exactly once).
// A: direct global->VGPR, depth-2 prefetch, 4 frags/iter (2 row-groups x
//    2 k-halves), named regs (no dynamic indexing).
// B: shared dbuf LDS (2x16 KB), XOR-swizzled granules both sides (0
//    conflicts, verified r1/r7).
// vmcnt (per iter issues S(it+1)=4, A(it+2)=4):
//   newest allowed = A(it+1)4 + S(it+1)4 + A(it+2)4 = 12 -> vmcnt(12)
//   it=16: A(18) absent -> vmcnt(8); final tile: vmcnt(0).
// Grid derives from BM via GEMM_GRID (r2/r3 bug class excluded).
__global__ __launch_bounds__(256) void mfma_gemm(const u16* __restrict__ xb,
                                                 const u16* __restrict__ sums,
                                                 const u16* __restrict__ wt9,
                                                 const float* __restrict__ bias,
                                                 float* __restrict__ out) {
    __shared__ __align__(16) u16 Bs[2][128 * 64];   // 32 KB

    const int tid  = threadIdx.x;
    const int wave = tid >> 6;
    const int lane = tid & 63;
    const int m0   = blockIdx.x * BM;
    const int fr   = lane & 15;
    const int l4   = lane >> 4;          // 0..3
    const int fk   = l4 * 8;

    // stage mapping: 1024 granules of 16B per buffer, 4 rounds x 256 thr.
    int boff[4];
#pragma unroll
    for (int r = 0; r < 4; ++r) {
        int p = r * 256 + tid;
        int g = p ^ ((p >> 3) & 7);
        boff[r] = (g >> 3) * D + (g & 7) * 8;     // u16 offset in [col][k] panel
    }
    // read mapping: frag (h,nt): logical g = (nt*16+fr)*8 + h*4 + l4
    int bidx[16];
#pragma unroll
    for (int h = 0; h < 2; ++h)
#pragma unroll
        for (int nt = 0; nt < 8; ++nt) {
            int gl = (nt * 16 + fr) * 8 + h * 4 + l4;
            int pp = gl ^ ((gl >> 3) & 7);
            bidx[h * 8 + nt] = pp * 8;             // u16 index
        }

    int r0 = m0 + wave * 32 + fr;       if (r0 > NN - 1) r0 = NN - 1;  // rows fr
    int r1 = m0 + wave * 32 + 16 + fr;  if (r1 > NN - 1) r1 = NN - 1;  // rows 16+fr
    const size_t aoff0 = (size_t)r0 * D + fk;
    const size_t aoff1 = (size_t)r1 * D + fk;

    auto stage = [&](u16* bufp, const u16* Bp) {
#pragma unroll
        for (int r = 0; r < 4; ++r)
            async_cp16(Bp + boff[r], (char*)bufp + (size_t)(r * 256 + tid) * 16);
    };

    f32x4 acc0[8], acc1[8];
#pragma unroll
    for (int j = 0; j < 8; ++j) {
        acc0[j] = (f32x4){0.f, 0.f, 0.f, 0.f};
        acc1[j] = (f32x4){0.f, 0.f, 0.f, 0.f};
    }

    // A frag slots: c = iter it, n1 = it+1, n2 = it+2.
    // index: 0 = (rowgrp0, khalf0), 1 = (rowgrp0, khalf1),
    //        2 = (rowgrp1, khalf0), 3 = (rowgrp1, khalf1)
    s16x8 a0c, a1c, a2c, a3c, a0n1, a1n1, a2n1, a3n1, a0n2, a1n2, a2n2, a3n2;

    // K-plan: 18 iters of BK=64; plane = it>>1 (0 = root/xb), kof = (it&1)*64
    // prologue: S(0) + A(0) + A(1)   (iters 0 and 1 are both plane 0)
    stage(&Bs[0][0], wt9);
    a0c  = *(const s16x8*)(xb + aoff0);          // A(0), kof 0
    a1c  = *(const s16x8*)(xb + aoff0 + 32);
    a2c  = *(const s16x8*)(xb + aoff1);
    a3c  = *(const s16x8*)(xb + aoff1 + 32);
    a0n1 = *(const s16x8*)(xb + aoff0 + 64);     // A(1), kof 64
    a1n1 = *(const s16x8*)(xb + aoff0 + 96);
    a2n1 = *(const s16x8*)(xb + aoff1 + 64);
    a3n1 = *(const s16x8*)(xb + aoff1 + 96);
    a0n2 = a0n1; a1n2 = a1n1; a2n2 = a2n1; a3n2 = a3n1;
    __builtin_amdgcn_sched_barrier(0);   // pin prologue VMEM group (FIFO count)

    for (int it = 0; it < 17; ++it) {
        const int nx  = it + 1;
        const int npl = nx >> 1;
        const int kof = (nx & 1) * 64;
        u16* nbuf = &Bs[nx & 1][0];
        const u16* cbuf = &Bs[it & 1][0];

        stage(nbuf, wt9 + npl * 16384 + kof);          // S(it+1): 4 cp16
        if (it + 2 <= 17) {                            // A(it+2): 4 loads
            const int p2 = (it + 2) >> 1;
            const int k2 = ((it + 2) & 1) * 64;
            const u16* Ap2 = ((p2 == 0) ? xb
                              : sums + (size_t)(p2 - 1) * NN * D) + k2;
            a0n2 = *(const s16x8*)(Ap2 + aoff0);
            a1n2 = *(const s16x8*)(Ap2 + aoff0 + 32);
            a2n2 = *(const s16x8*)(Ap2 + aoff1);
            a3n2 = *(const s16x8*)(Ap2 + aoff1 + 32);
        }
        __builtin_amdgcn_sched_barrier(0);
        if (it < 16) { asm volatile("s_waitcnt vmcnt(12)" ::: "memory"); }
        else         { asm volatile("s_waitcnt vmcnt(8)"  ::: "memory"); }
        __builtin_amdgcn_s_barrier();                  // all waves: cbuf ready
        __builtin_amdgcn_sched_barrier(0);             // no ds_read hoists above
#pragma unroll
        for (int nt = 0; nt < 8; ++nt) {               // khalf 0: 1 read, 2 MFMA
            s16x8 bf = *(const s16x8*)(cbuf + bidx[nt]);
            acc0[nt] = __builtin_amdgcn_mfma_f32_16x16x32_bf16(a0c, bf, acc0[nt], 0, 0, 0);
            acc1[nt] = __builtin_amdgcn_mfma_f32_16x16x32_bf16(a2c, bf, acc1[nt], 0, 0, 0);
        }
#pragma unroll
        for (int nt = 0; nt < 8; ++nt) {               // khalf 1
            s16x8 bf = *(const s16x8*)(cbuf + bidx[8 + nt]);
            acc0[nt] = __builtin_amdgcn_mfma_f32_16x16x32_bf16(a1c, bf, acc0[nt], 0, 0, 0);
            acc1[nt] = __builtin_amdgcn_mfma_f32_16x16x32_bf16(a3c, bf, acc1[nt], 0, 0, 0);
        }
        asm volatile("s_waitcnt lgkmcnt(0)" ::: "memory"); // reads of cbuf done
        __builtin_amdgcn_sched_barrier(0);
        __builtin_amdgcn_s_barrier();                      // WAR guard
        __builtin_amdgcn_sched_barrier(0);                 // no next-stage hoists
        a0c = a0n1; a1c = a1n1; a2c = a2n1; a3c = a3n1;    // rotate A queue
        a0n1 = a0n2; a1n1 = a1n2; a2n1 = a2n2; a3n1 = a3n2;
    }
    // final tile (it=17, buffer 1): full drain ok, nothing left to overlap
    asm volatile("s_waitcnt vmcnt(0)" ::: "memory");
    __builtin_amdgcn_s_barrier();
    __builtin_amdgcn_sched_barrier(0);
    {
        const u16* cbuf = &Bs[1][0];
#pragma unroll
        for (int nt = 0; nt < 8; ++nt) {
            s16x8 bf = *(const s16x8*)(cbuf + bidx[nt]);
            acc0[nt] = __builtin_amdgcn_mfma_f32_16x16x32_bf16(a0c, bf, acc0[nt], 0, 0, 0);
            acc1[nt] = __builtin_amdgcn_mfma_f32_16x16x32_bf16(a2c, bf, acc1[nt], 0, 0, 0);
        }
#pragma unroll
        for (int nt = 0; nt < 8; ++nt) {
            s16x8 bf = *(const s16x8*)(cbuf + bidx[8 + nt]);
            acc0[nt] = __builtin_amdgcn_mfma_f32_16x16x32_bf16(a1c, bf, acc0[nt], 0, 0, 0);
            acc1[nt] = __builtin_amdgcn_mfma_f32_16x16x32_bf16(a3c, bf, acc1[nt], 0, 0, 0);
        }
    }

    // epilogue: C/D layout col=lane&15, row=(lane>>4)*4+reg; 2 row-groups
    const int cl = lane & 15;
    const int rq = l4 * 4;
#pragma unroll
    for (int nt = 0; nt < 8; ++nt) {
        int col = nt * 16 + cl;
        float bv = bias[col];
#pragma unroll
        for (int reg = 0; reg < 4; ++reg) {
            int n = m0 + wave * 32 + rq + reg;
            if (n < NN) {
                float v = acc0[nt][reg] + bv;
                out[(size_t)n * D + col] = fmaxf(v, 0.0f);
            }
            int n2 = n + 16;
            if (n2 < NN) {
                float v = acc1[nt][reg] + bv;
                out[(size_t)n2 * D + col] = fmaxf(v, 0.0f);
            }
        }
    }
}

extern "C" void kernel_launch(void* const* d_in, const int* in_sizes, int n_in,
                              void* d_out, int out_size, void* d_ws, size_t ws_size,
                              hipStream_t stream) {
    const float* x      = (const float*)d_in[0];
    const int*   ei     = (const int*)d_in[1];
    const int*   et     = (const int*)d_in[2];
    const float* weight = (const float*)d_in[3];
    const float* root   = (const float*)d_in[4];
    const float* bias   = (const float*)d_in[5];
    float* out = (float*)d_out;
    const int* srcv = ei;
    const int* dstv = ei + NE;

    // ws: ints [cnt2 NSEG][cur2 NSEG][offs2 NSEG+1][bsums 512][ebin NE],
    // then u16 [xb NN*D][sums NR*NN*D][wt9 9*D*D]
    int* cnt2  = (int*)d_ws;
    int* cur2  = cnt2 + NSEG;
    int* offs2 = cur2 + NSEG;
    int* bsums = offs2 + NSEG + 1;
    int* ebin  = bsums + 512;
    size_t fixed_b  = ((char*)(ebin + NE) - (char*)d_ws);
    size_t fixed_al = (fixed_b + 255) & ~(size_t)255;
    u16* xb   = (u16*)((char*)d_ws + fixed_al);
    u16* sums = xb + (size_t)NN * D;
    u16* wt9  = sums + (size_t)NR * NN * D;

    hipMemsetAsync(cnt2, 0, NSEG * sizeof(int), stream);

    const int PREP = NN * D / 4 + (NR + 1) * D * D + NE;
    prep_all<<<(PREP + 255) / 256, 256, 0, stream>>>(x, weight, root, dstv, et,
                                                     xb, wt9, cnt2);

    scan1<<<NBLK2, 256, 0, stream>>>(cnt2, offs2, bsums);
    scan2<<<1, 512, 0, stream>>>(bsums);
    scan3<<<(NSEG + 256) / 256, 256, 0, stream>>>(offs2, cur2, bsums);
    fill_bins<<<(NE + 255) / 256, 256, 0, stream>>>(srcv, dstv, et, cur2, ebin);

    aggregate_kernel<<<(NN + 1) / 2, 128, 0, stream>>>((const u32*)xb, offs2, ebin,
                                                       (u32*)sums);

    mfma_gemm<<<GEMM_GRID, 256, 0, stream>>>(xb, sums, wt9, bias, out);
}